// Round 4
// baseline (2636.189 us; speedup 1.0000x reference)
//
#include <hip/hip_runtime.h>

// Problem constants.
#define E_TOT   500000
#define N_NEW_  100000
#define H_      128
#define D_      100
#define NBLK2   ((E_TOT + 63) / 64)     // 7813
#define PERM2   (NBLK2 * 64)            // 500032

typedef short bf16x8 __attribute__((ext_vector_type(8)));
typedef float f32x4  __attribute__((ext_vector_type(4)));

__device__ __forceinline__ unsigned short f2bf(float f) {
  unsigned u = __float_as_uint(f);
  u += 0x7fffu + ((u >> 16) & 1u);       // RNE
  return (unsigned short)(u >> 16);
}
__device__ __forceinline__ float bf2f(unsigned short u) {
  return __uint_as_float(((unsigned)u) << 16);
}
__device__ __forceinline__ float sigm(float x) { return 1.f / (1.f + expf(-x)); }

// dst[c*R + r] = src[r*C + c]
__global__ void k_transpose(const float* __restrict__ src, float* __restrict__ dst, int R, int C) {
  int idx = blockIdx.x * 256 + threadIdx.x;
  if (idx < R * C) {
    int r = idx / C, c = idx - r * C;
    dst[(size_t)c * R + r] = src[idx];
  }
}

// Weight atlas 640 rows x 256 cols bf16. Cols: [0:128]=hs-region, [128:256]=he-region(100+pad0).
// Chunk0 (rows 0-127): logit = Ws | 0.
// Chunks 1-4 (h-slice s=c-1): rows gg*32+h' (gg: 0=r,1=z,2=xn,3=hn), h=s*32+h':
//   hs cols: Whh rows {h, 128+h, -, 256+h} (xn=0) ; he cols: Wih[:, :100] rows {h,128+h,256+h,-} (hn=0)
__global__ void k_prep(const float* __restrict__ Ws, const float* __restrict__ Wih,
                       const float* __restrict__ Whh, unsigned short* __restrict__ Wcat) {
  int idx = blockIdx.x * 256 + threadIdx.x;
  if (idx >= 640 * 256) return;
  int o = idx >> 8, k = idx & 255;
  int rg = k >> 7, cr = k & 127;
  int ch = o >> 7, oo = o & 127;
  float v = 0.f;
  if (ch == 0) {
    if (rg == 0) v = Ws[oo * 128 + cr];
  } else {
    int s = ch - 1, gg = oo >> 5, h = s * 32 + (oo & 31);
    if (rg == 0) {
      if (gg == 0) v = Whh[h * 128 + cr];
      else if (gg == 1) v = Whh[(128 + h) * 128 + cr];
      else if (gg == 3) v = Whh[(256 + h) * 128 + cr];
    } else if (cr < 100) {
      if (gg == 0) v = Wih[h * 200 + cr];
      else if (gg == 1) v = Wih[(128 + h) * 200 + cr];
      else if (gg == 2) v = Wih[(256 + h) * 200 + cr];
    }
  }
  Wcat[idx] = f2bf(v);
}

// Per-relation projections (500 rels): P_r = hr@Wr^T, P_qr = qr@Wqr^T + b_qr,
// P_ihr[g] = hr@Wih[:,100:200]^T + b_ih + (g<256 ? b_hh : 0)
__global__ void k_projrel(const float* __restrict__ rel_table,
                          const float* __restrict__ Wr, const float* __restrict__ Wqr,
                          const float* __restrict__ Wih,
                          const float* __restrict__ b_qr, const float* __restrict__ b_ih,
                          const float* __restrict__ b_hh,
                          float* __restrict__ P_r, float* __restrict__ P_qr,
                          float* __restrict__ P_ihr) {
  __shared__ float rrow[100];
  int r = blockIdx.x, t = threadIdx.x;
  if (t < 100) rrow[t] = rel_table[r * 100 + t];
  __syncthreads();
  for (int o = t; o < 640; o += 256) {
    float s = 0.f;
    if (o < 128) {
      for (int k = 0; k < 100; ++k) s += rrow[k] * Wr[o * 100 + k];
      P_r[r * 128 + o] = s;
    } else if (o < 256) {
      int h = o - 128;
      for (int k = 0; k < 100; ++k) s += rrow[k] * Wqr[h * 100 + k];
      P_qr[r * 128 + h] = s + b_qr[h];
    } else {
      int g = o - 256;
      for (int k = 0; k < 100; ++k) s += rrow[k] * Wih[g * 200 + 100 + k];
      P_ihr[r * 384 + g] = s + b_ih[g] + (g < 256 ? b_hh[g] : 0.f);
    }
  }
}

// ---- counting sort of edges by tail ----
__global__ void k_hist(const int* __restrict__ tail, int* __restrict__ cnt) {
  int e = blockIdx.x * 256 + threadIdx.x;
  if (e < E_TOT) atomicAdd(&cnt[tail[e]], 1);
}
__global__ void k_scan1(int* __restrict__ cnt, int* __restrict__ bsum) {
  __shared__ int s[512];
  int gid = blockIdx.x * 512 + threadIdx.x;
  int v = (gid < N_NEW_) ? cnt[gid] : 0;
  s[threadIdx.x] = v;
  __syncthreads();
  for (int off = 1; off < 512; off <<= 1) {
    int add = (threadIdx.x >= off) ? s[threadIdx.x - off] : 0;
    __syncthreads();
    s[threadIdx.x] += add;
    __syncthreads();
  }
  if (gid < N_NEW_) cnt[gid] = s[threadIdx.x] - v;     // exclusive
  if (threadIdx.x == 511) bsum[blockIdx.x] = s[511];
}
// parallel scan of the 196 block sums (single block, 256 threads)
__global__ void k_scan2(int* __restrict__ bsum, int nb) {
  __shared__ int wsum[4];
  int t = threadIdx.x;
  int v = (t < nb) ? bsum[t] : 0;
  int x = v;
  for (int off = 1; off < 64; off <<= 1) {
    int y = __shfl_up(x, off);
    if ((t & 63) >= off) x += y;
  }
  if ((t & 63) == 63) wsum[t >> 6] = x;
  __syncthreads();
  int add = 0;
  for (int w = 0; w < (t >> 6); ++w) add += wsum[w];
  if (t < nb) bsum[t] = x - v + add;                    // exclusive
}
__global__ void k_scan3(int* __restrict__ cnt, const int* __restrict__ bsum) {
  int i = blockIdx.x * 256 + threadIdx.x;
  if (i < N_NEW_) cnt[i] += bsum[i >> 9];
}
// scatter edge attributes into tail-sorted arrays
__global__ void k_scatter5(const int* __restrict__ head, const int* __restrict__ rel,
                           const int* __restrict__ ent, const int* __restrict__ tail,
                           const int* __restrict__ qidx, int* __restrict__ cur,
                           int* __restrict__ gsh, int* __restrict__ gsr, int* __restrict__ gse,
                           int* __restrict__ gst, int* __restrict__ gsq) {
  int e = blockIdx.x * 256 + threadIdx.x;
  if (e < E_TOT) {
    int tl = tail[e];
    int pos = atomicAdd(&cur[tl], 1);
    gsh[pos] = head[e]; gsr[pos] = rel[e]; gse[pos] = ent[e];
    gst[pos] = tl;      gsq[pos] = qidx[e];
  }
}

// ---- Fused edge kernel: 64 sorted edges/block, 320 threads = 5 waves (chunk each).
// Stage hs+he once -> 8 K-tile MFMA (no barriers) -> in-register gates -> msg bf16 LDS
// -> run-accumulated scatter. 2 barriers total. 3 blocks/CU.
__global__ __launch_bounds__(320, 4) void k_edge(
    const int* __restrict__ gsh, const int* __restrict__ gsr, const int* __restrict__ gse,
    const int* __restrict__ gst, const int* __restrict__ gsq,
    const float* __restrict__ node_emb, const float* __restrict__ ent_table,
    const unsigned short* __restrict__ Wcat,
    const float* __restrict__ P_r, const float* __restrict__ P_qr,
    const float* __restrict__ P_ihr,
    const float* __restrict__ Wa, const float* __restrict__ b_a,
    const float* __restrict__ b_hh,
    float* __restrict__ den, float* __restrict__ agg)
{
  __shared__ __align__(16) unsigned short A0[64][136];   // hs bf16 (persistent)
  __shared__ __align__(16) unsigned short A1[64][136];   // he bf16
  __shared__ unsigned short msg_s[64][130];
  __shared__ float ex_s[64];
  __shared__ int tl_s[64], rl_s[64], q_s[64];

  const int t = threadIdx.x;
  const int wid = t >> 6, lane = t & 63;
  const int c = wid;                       // chunk 0..4
  const int l15 = lane & 15, l4 = lane >> 4;
  const int e0 = blockIdx.x * 64;

  if (t < 64) {
    tl_s[t] = gst[e0 + t];
    rl_s[t] = gsr[e0 + t];
    q_s[t]  = gsq[e0 + t];
  }
  if (t < 256) {
    const int sedge = t >> 2, qq = t & 3;
    const int hidx = gsh[e0 + sedge], eidx = gse[e0 + sedge];
    const float* hrow = node_emb + (size_t)hidx * 128;
    const float* erow = ent_table + (size_t)eidx * 100;
#pragma unroll
    for (int j = 0; j < 4; ++j) {
      int c0 = j * 32 + qq * 8;
      float4 v0 = *(const float4*)(hrow + c0);
      float4 v1 = *(const float4*)(hrow + c0 + 4);
      bf16x8 pk;
      pk[0] = (short)f2bf(v0.x); pk[1] = (short)f2bf(v0.y);
      pk[2] = (short)f2bf(v0.z); pk[3] = (short)f2bf(v0.w);
      pk[4] = (short)f2bf(v1.x); pk[5] = (short)f2bf(v1.y);
      pk[6] = (short)f2bf(v1.z); pk[7] = (short)f2bf(v1.w);
      *(bf16x8*)&A0[sedge][c0] = pk;
    }
#pragma unroll
    for (int j = 0; j < 4; ++j) {
      int c0 = j * 32 + qq * 8;
      bf16x8 pk;
      if (c0 + 8 <= 100) {
        float4 v0 = *(const float4*)(erow + c0);
        float4 v1 = *(const float4*)(erow + c0 + 4);
        pk[0] = (short)f2bf(v0.x); pk[1] = (short)f2bf(v0.y);
        pk[2] = (short)f2bf(v0.z); pk[3] = (short)f2bf(v0.w);
        pk[4] = (short)f2bf(v1.x); pk[5] = (short)f2bf(v1.y);
        pk[6] = (short)f2bf(v1.z); pk[7] = (short)f2bf(v1.w);
      } else {
#pragma unroll
        for (int u = 0; u < 8; ++u) {
          float g = (c0 + u < 100) ? erow[c0 + u] : 0.f;
          pk[u] = (short)f2bf(g);
        }
      }
      *(bf16x8*)&A1[sedge][c0] = pk;
    }
  }
  __syncthreads();

  f32x4 acc[4][8];
  const f32x4 zz = {0.f, 0.f, 0.f, 0.f};
#pragma unroll
  for (int i = 0; i < 4; ++i)
#pragma unroll
    for (int j = 0; j < 8; ++j) acc[i][j] = zz;

  const unsigned short* wbase = Wcat + (size_t)c * 128 * 256;
  const int nkt = (c == 0) ? 4 : 8;
  for (int kt = 0; kt < nkt; ++kt) {
    bf16x8 bfr[8], afr[4];
#pragma unroll
    for (int ni = 0; ni < 8; ++ni)
      bfr[ni] = *(const bf16x8*)(wbase + (size_t)(ni * 16 + l15) * 256 + kt * 32 + l4 * 8);
    const int ci = (kt & 3) * 32 + l4 * 8;
    if (kt < 4) {
#pragma unroll
      for (int mi = 0; mi < 4; ++mi) afr[mi] = *(const bf16x8*)&A0[mi * 16 + l15][ci];
    } else {
#pragma unroll
      for (int mi = 0; mi < 4; ++mi) afr[mi] = *(const bf16x8*)&A1[mi * 16 + l15][ci];
    }
#pragma unroll
    for (int mi = 0; mi < 4; ++mi)
#pragma unroll
      for (int ni = 0; ni < 8; ++ni)
        acc[mi][ni] = __builtin_amdgcn_mfma_f32_16x16x32_bf16(afr[mi], bfr[ni], acc[mi][ni], 0, 0, 0);
  }

  // ---- epilogue (no barrier yet: per-wave work on own acc) ----
  if (c == 0) {
    // logit: pre = acc + P_r[rel] + P_qr[q]; ex = exp(sum_h Wa*relu(pre) + b_a)
    float ba = b_a[0];
#pragma unroll
    for (int mi = 0; mi < 4; ++mi) {
      float p[4] = {0.f, 0.f, 0.f, 0.f};
#pragma unroll
      for (int r = 0; r < 4; ++r) {
        int el = mi * 16 + l4 * 4 + r;
        const float* pr = P_r + (size_t)rl_s[el] * 128;
        const float* pq = P_qr + (size_t)q_s[el] * 128;
#pragma unroll
        for (int ni = 0; ni < 8; ++ni) {
          int h = ni * 16 + l15;
          float pre = acc[mi][ni][r] + pr[h] + pq[h];
          p[r] += Wa[h] * fmaxf(pre, 0.f);
        }
      }
#pragma unroll
      for (int off = 1; off < 16; off <<= 1) {
#pragma unroll
        for (int r = 0; r < 4; ++r) p[r] += __shfl_xor(p[r], off);
      }
      if (l15 == 0) {
#pragma unroll
        for (int r = 0; r < 4; ++r)
          ex_s[mi * 16 + l4 * 4 + r] = expf(p[r] + ba);
      }
    }
  } else {
    // gates fully in-register: acc[mi][ni]: ni = gate*2 + hsel; h = s*32 + hsel*16 + l15
    const int s = c - 1;
    const int h0 = s * 32 + l15, h1 = h0 + 16;
    const float bh0 = b_hh[256 + h0], bh1 = b_hh[256 + h1];
#pragma unroll
    for (int mi = 0; mi < 4; ++mi) {
#pragma unroll
      for (int r = 0; r < 4; ++r) {
        int el = mi * 16 + l4 * 4 + r;
        const float* Pb = P_ihr + (size_t)rl_s[el] * 384;
        float r0 = sigm(acc[mi][0][r] + Pb[h0]);
        float r1 = sigm(acc[mi][1][r] + Pb[h1]);
        float z0 = sigm(acc[mi][2][r] + Pb[128 + h0]);
        float z1 = sigm(acc[mi][3][r] + Pb[128 + h1]);
        float n0 = tanhf(acc[mi][4][r] + Pb[256 + h0] + r0 * (acc[mi][6][r] + bh0));
        float n1 = tanhf(acc[mi][5][r] + Pb[256 + h1] + r1 * (acc[mi][7][r] + bh1));
        float hs0 = bf2f(A0[el][h0]), hs1 = bf2f(A0[el][h1]);
        msg_s[el][h0] = f2bf((1.f - z0) * n0 + z0 * hs0);
        msg_s[el][h1] = f2bf((1.f - z1) * n1 + z1 * hs1);
      }
    }
  }
  __syncthreads();

  // ---- den (t<64) + run-accumulated agg scatter (t 64..319) ----
  if (t < 64) {
    int tl = tl_s[t];
    bool lead = (tl >= 0) && (t == 0 || tl_s[t - 1] != tl);
    if (lead) {
      float ssum = 0.f;
      int i = t;
      while (i < 64 && tl_s[i] == tl) { ssum += ex_s[i]; ++i; }
      atomicAdd(&den[tl], ssum);
    }
  } else {
    int ti = t - 64;
    int h = ti & 127, half = ti >> 7;
    float run = 0.f;
    int rt = -1;
    for (int k2 = 0; k2 < 32; ++k2) {
      int el = half * 32 + k2;
      int tl = tl_s[el];
      if (tl >= 0) {
        float v = ex_s[el] * bf2f(msg_s[el][h]);
        if (tl != rt) {
          if (rt >= 0) atomicAdd(&agg[(size_t)rt * H_ + h], run);
          run = 0.f; rt = tl;
        }
        run += v;
      }
    }
    if (rt >= 0) atomicAdd(&agg[(size_t)rt * H_ + h], run);
  }
}

// ---- out = LayerNorm(relu((agg_raw/(den+eps)) @ Wh^T)), in place over d_out ----
__global__ __launch_bounds__(256) void k_out(
    const float* __restrict__ WhT, const float* __restrict__ ln_g, const float* __restrict__ ln_b,
    const float* __restrict__ den, float* __restrict__ out)
{
  __shared__ __align__(16) float a_s[16][H_];
  __shared__ float o_s[16][H_];
  __shared__ float mu_s[16], rs_s[16];
  const int tid = threadIdx.x;
  const size_t r0 = (size_t)blockIdx.x * 16;

  for (int idx = tid; idx < 16 * H_; idx += 256) {
    int r = idx >> 7, j = idx & (H_ - 1);
    float dv = den[r0 + r] + 1e-6f;
    a_s[r][j] = out[(r0 + r) * H_ + j] / dv;
  }
  __syncthreads();

  const int col = tid & 15, rr = tid >> 4;
  float acc[8] = {};
  for (int k4 = 0; k4 < H_ / 4; ++k4) {
    float4 a = ((const float4*)a_s[rr])[k4];
#pragma unroll
    for (int kk = 0; kk < 4; ++kk) {
      const float4* wrow = (const float4*)(WhT + (size_t)(k4 * 4 + kk) * H_);
      float av = ((const float*)&a)[kk];
      float4 w0 = wrow[col];
      float4 w1 = wrow[16 + col];
      acc[0] += av * w0.x; acc[1] += av * w0.y; acc[2] += av * w0.z; acc[3] += av * w0.w;
      acc[4] += av * w1.x; acc[5] += av * w1.y; acc[6] += av * w1.z; acc[7] += av * w1.w;
    }
  }
  float s = 0.f, sq = 0.f;
#pragma unroll
  for (int ci = 0; ci < 8; ++ci) {
    float v = fmaxf(acc[ci], 0.f);
    acc[ci] = v; s += v; sq += v * v;
  }
#pragma unroll
  for (int ci = 0; ci < 4; ++ci) {
    o_s[rr][col * 4 + ci]      = acc[ci];
    o_s[rr][64 + col * 4 + ci] = acc[4 + ci];
  }
#pragma unroll
  for (int off = 1; off < 16; off <<= 1) { s += __shfl_xor(s, off); sq += __shfl_xor(sq, off); }
  if (col == 0) {
    float mu = s * (1.f / H_);
    mu_s[rr] = mu;
    rs_s[rr] = rsqrtf(sq * (1.f / H_) - mu * mu + 1e-5f);
  }
  __syncthreads();
  for (int idx = tid; idx < 16 * H_; idx += 256) {
    int r = idx >> 7, j = idx & (H_ - 1);
    out[(r0 + r) * H_ + j] = ln_g[j] * (o_s[r][j] - mu_s[r]) * rs_s[r] + ln_b[j];
  }
}

extern "C" void kernel_launch(void* const* d_in, const int* in_sizes, int n_in,
                              void* d_out, int out_size, void* d_ws, size_t ws_size,
                              hipStream_t stream) {
  (void)in_sizes; (void)n_in; (void)ws_size;
  const int* head = (const int*)d_in[0];
  const int* rel  = (const int*)d_in[1];
  const int* ent  = (const int*)d_in[2];
  const int* tail = (const int*)d_in[3];
  const int* qidx = (const int*)d_in[4];
  const float* node_emb  = (const float*)d_in[5];
  const float* ent_table = (const float*)d_in[6];
  const float* rel_table = (const float*)d_in[7];
  const float* Ws   = (const float*)d_in[8];
  const float* Wr   = (const float*)d_in[9];
  const float* Wqr  = (const float*)d_in[10];
  const float* b_qr = (const float*)d_in[11];
  const float* Wa   = (const float*)d_in[12];
  const float* b_a  = (const float*)d_in[13];
  const float* W_ih = (const float*)d_in[14];
  const float* W_hh = (const float*)d_in[15];
  const float* b_ih = (const float*)d_in[16];
  const float* b_hh = (const float*)d_in[17];
  const float* Wh   = (const float*)d_in[18];
  const float* ln_g = (const float*)d_in[19];
  const float* ln_b = (const float*)d_in[20];
  float* out = (float*)d_out;

  // ws layout (bytes):
  char* w = (char*)d_ws;
  float* den  = (float*)w;                         w += 400000;
  unsigned short* Wcat = (unsigned short*)w;       w += 640 * 256 * 2;     // 327,680
  float* WhT  = (float*)w;                         w += 65536;
  float* P_r  = (float*)w;                         w += 500 * 128 * 4;     // 256,000
  float* P_qr = (float*)w;                         w += 500 * 128 * 4;
  float* P_ihr= (float*)w;                         w += 500 * 384 * 4;     // 768,000
  int* cnt    = (int*)w;                           w += 400000;
  int* bsum   = (int*)w;                           w += 1024;
  int* gsh    = (int*)w;                           w += PERM2 * 4;
  int* gsr    = (int*)w;                           w += PERM2 * 4;
  int* gse    = (int*)w;                           w += PERM2 * 4;
  int* gst    = (int*)w;                           w += PERM2 * 4;
  int* gsq    = (int*)w;                           w += PERM2 * 4;

  hipMemsetAsync(den, 0, N_NEW_ * sizeof(float), stream);
  hipMemsetAsync(d_out, 0, (size_t)out_size * sizeof(float), stream);
  hipMemsetAsync(cnt, 0, N_NEW_ * sizeof(int), stream);
  // pad entries (E_TOT..PERM2): safe table index 0, tail = -1
  hipMemsetAsync(gsh + E_TOT, 0, (PERM2 - E_TOT) * sizeof(int), stream);
  hipMemsetAsync(gsr + E_TOT, 0, (PERM2 - E_TOT) * sizeof(int), stream);
  hipMemsetAsync(gse + E_TOT, 0, (PERM2 - E_TOT) * sizeof(int), stream);
  hipMemsetAsync(gsq + E_TOT, 0, (PERM2 - E_TOT) * sizeof(int), stream);
  hipMemsetAsync(gst + E_TOT, 0xFF, (PERM2 - E_TOT) * sizeof(int), stream);

  k_prep<<<(640 * 256 + 255) / 256, 256, 0, stream>>>(Ws, W_ih, W_hh, Wcat);
  k_transpose<<<(128 * 128 + 255) / 256, 256, 0, stream>>>(Wh, WhT, 128, 128);
  k_projrel<<<500, 256, 0, stream>>>(rel_table, Wr, Wqr, W_ih, b_qr, b_ih, b_hh,
                                     P_r, P_qr, P_ihr);

  // counting sort by tail -> sorted attribute arrays
  k_hist<<<(E_TOT + 255) / 256, 256, 0, stream>>>(tail, cnt);
  k_scan1<<<(N_NEW_ + 511) / 512, 512, 0, stream>>>(cnt, bsum);
  k_scan2<<<1, 256, 0, stream>>>(bsum, (N_NEW_ + 511) / 512);
  k_scan3<<<(N_NEW_ + 255) / 256, 256, 0, stream>>>(cnt, bsum);
  k_scatter5<<<(E_TOT + 255) / 256, 256, 0, stream>>>(head, rel, ent, tail, qidx, cnt,
                                                      gsh, gsr, gse, gst, gsq);

  k_edge<<<NBLK2, 320, 0, stream>>>(
      gsh, gsr, gse, gst, gsq, node_emb, ent_table, Wcat,
      P_r, P_qr, P_ihr, Wa, b_a, b_hh, den, out);

  k_out<<<N_NEW_ / 16, 256, 0, stream>>>(WhT, ln_g, ln_b, den, out);
}

// Round 6
// 1305.824 us; speedup vs baseline: 2.0188x; 2.0188x over previous
//
#include <hip/hip_runtime.h>

// Problem constants.
#define E_TOT   500000
#define N_NEW_  100000
#define H_      128
#define D_      100
#define NBLK2   ((E_TOT + 63) / 64)     // 7813
#define PERM2   (NBLK2 * 64)            // 500032

typedef short bf16x8 __attribute__((ext_vector_type(8)));
typedef float f32x4  __attribute__((ext_vector_type(4)));

__device__ __forceinline__ unsigned short f2bf(float f) {
  unsigned u = __float_as_uint(f);
  u += 0x7fffu + ((u >> 16) & 1u);       // RNE
  return (unsigned short)(u >> 16);
}
__device__ __forceinline__ float bf2f(unsigned short u) {
  return __uint_as_float(((unsigned)u) << 16);
}
__device__ __forceinline__ float sigm(float x) { return 1.f / (1.f + expf(-x)); }

// dst[c*R + r] = src[r*C + c]
__global__ void k_transpose(const float* __restrict__ src, float* __restrict__ dst, int R, int C) {
  int idx = blockIdx.x * 256 + threadIdx.x;
  if (idx < R * C) {
    int r = idx / C, c = idx - r * C;
    dst[(size_t)c * R + r] = src[idx];
  }
}

// Weight atlas 640 rows x 256 cols bf16 (unchanged from R4; R4 passed numerically).
__global__ void k_prep(const float* __restrict__ Ws, const float* __restrict__ Wih,
                       const float* __restrict__ Whh, unsigned short* __restrict__ Wcat) {
  int idx = blockIdx.x * 256 + threadIdx.x;
  if (idx >= 640 * 256) return;
  int o = idx >> 8, k = idx & 255;
  int rg = k >> 7, cr = k & 127;
  int ch = o >> 7, oo = o & 127;
  float v = 0.f;
  if (ch == 0) {
    if (rg == 0) v = Ws[oo * 128 + cr];
  } else {
    int s = ch - 1, gg = oo >> 5, h = s * 32 + (oo & 31);
    if (rg == 0) {
      if (gg == 0) v = Whh[h * 128 + cr];
      else if (gg == 1) v = Whh[(128 + h) * 128 + cr];
      else if (gg == 3) v = Whh[(256 + h) * 128 + cr];
    } else if (cr < 100) {
      if (gg == 0) v = Wih[h * 200 + cr];
      else if (gg == 1) v = Wih[(128 + h) * 200 + cr];
      else if (gg == 2) v = Wih[(256 + h) * 200 + cr];
    }
  }
  Wcat[idx] = f2bf(v);
}

// Per-relation projections (500 rels).
__global__ void k_projrel(const float* __restrict__ rel_table,
                          const float* __restrict__ Wr, const float* __restrict__ Wqr,
                          const float* __restrict__ Wih,
                          const float* __restrict__ b_qr, const float* __restrict__ b_ih,
                          const float* __restrict__ b_hh,
                          float* __restrict__ P_r, float* __restrict__ P_qr,
                          float* __restrict__ P_ihr) {
  __shared__ float rrow[100];
  int r = blockIdx.x, t = threadIdx.x;
  if (t < 100) rrow[t] = rel_table[r * 100 + t];
  __syncthreads();
  for (int o = t; o < 640; o += 256) {
    float s = 0.f;
    if (o < 128) {
      for (int k = 0; k < 100; ++k) s += rrow[k] * Wr[o * 100 + k];
      P_r[r * 128 + o] = s;
    } else if (o < 256) {
      int h = o - 128;
      for (int k = 0; k < 100; ++k) s += rrow[k] * Wqr[h * 100 + k];
      P_qr[r * 128 + h] = s + b_qr[h];
    } else {
      int g = o - 256;
      for (int k = 0; k < 100; ++k) s += rrow[k] * Wih[g * 200 + 100 + k];
      P_ihr[r * 384 + g] = s + b_ih[g] + (g < 256 ? b_hh[g] : 0.f);
    }
  }
}

// ---- counting sort of edges by tail ----
__global__ void k_hist(const int* __restrict__ tail, int* __restrict__ cnt) {
  int e = blockIdx.x * 256 + threadIdx.x;
  if (e < E_TOT) atomicAdd(&cnt[tail[e]], 1);
}
__global__ void k_scan1(int* __restrict__ cnt, int* __restrict__ bsum) {
  __shared__ int s[512];
  int gid = blockIdx.x * 512 + threadIdx.x;
  int v = (gid < N_NEW_) ? cnt[gid] : 0;
  s[threadIdx.x] = v;
  __syncthreads();
  for (int off = 1; off < 512; off <<= 1) {
    int add = (threadIdx.x >= off) ? s[threadIdx.x - off] : 0;
    __syncthreads();
    s[threadIdx.x] += add;
    __syncthreads();
  }
  if (gid < N_NEW_) cnt[gid] = s[threadIdx.x] - v;     // exclusive
  if (threadIdx.x == 511) bsum[blockIdx.x] = s[511];
}
__global__ void k_scan2(int* __restrict__ bsum, int nb) {
  __shared__ int wsum[4];
  int t = threadIdx.x;
  int v = (t < nb) ? bsum[t] : 0;
  int x = v;
  for (int off = 1; off < 64; off <<= 1) {
    int y = __shfl_up(x, off);
    if ((t & 63) >= off) x += y;
  }
  if ((t & 63) == 63) wsum[t >> 6] = x;
  __syncthreads();
  int add = 0;
  for (int w = 0; w < (t >> 6); ++w) add += wsum[w];
  if (t < nb) bsum[t] = x - v + add;                    // exclusive
}
__global__ void k_scan3(int* __restrict__ cnt, const int* __restrict__ bsum) {
  int i = blockIdx.x * 256 + threadIdx.x;
  if (i < N_NEW_) cnt[i] += bsum[i >> 9];
}
// scatter packed edge attrs into tail-sorted int4 array: {head|rel<<17, ent|q<<17, tail, 0}
__global__ void k_scatterp(const int* __restrict__ head, const int* __restrict__ rel,
                           const int* __restrict__ ent, const int* __restrict__ tail,
                           const int* __restrict__ qidx, int* __restrict__ cur,
                           int4* __restrict__ gs4) {
  int e = blockIdx.x * 256 + threadIdx.x;
  if (e < E_TOT) {
    int tl = tail[e];
    int pos = atomicAdd(&cur[tl], 1);
    gs4[pos] = make_int4(head[e] | (rel[e] << 17), ent[e] | (qidx[e] << 17), tl, 0);
  }
}

// ---- Fused edge kernel: 64 sorted edges/block, 640 threads = 10 waves (5 chunks x 2 M-halves).
// acc[2][8] = 64 regs/thread (no spill). LDS 36 KB -> 3 blocks/CU.
__global__ __launch_bounds__(640) void k_edge(
    const int4* __restrict__ gs4,
    const float* __restrict__ node_emb, const float* __restrict__ ent_table,
    const unsigned short* __restrict__ Wcat,
    const float* __restrict__ P_r, const float* __restrict__ P_qr,
    const float* __restrict__ P_ihr,
    const float* __restrict__ Wa, const float* __restrict__ b_a,
    const float* __restrict__ b_hh,
    float* __restrict__ den, float* __restrict__ agg)
{
  __shared__ __align__(16) char smem[2 * 64 * 136 * 2];              // A0 | A1 (bf16)
  unsigned short (*A0)[136] = (unsigned short (*)[136])smem;
  unsigned short (*A1)[136] = (unsigned short (*)[136])(smem + 64 * 136 * 2);
  unsigned short (*msg_s)[136] = A1;                                 // alias: A1 dead post-MFMA
  __shared__ float ex_s[64];
  __shared__ int tl_s[64], rl_s[64], q_s[64], hd_s[64], en_s[64];

  const int t = threadIdx.x;
  const int wid = t >> 6, lane = t & 63;
  const int c = wid >> 1, wm = wid & 1;    // chunk 0..4, M-half
  const int l15 = lane & 15, l4 = lane >> 4;
  const int e0 = blockIdx.x * 64;

  if (t < 64) {
    int4 g = gs4[e0 + t];
    int tl = g.z;
    if (tl < 0) { g.x = 0; g.y = 0; }     // pad: safe table indices
    tl_s[t] = tl;
    hd_s[t] = g.x & 0x1FFFF;  rl_s[t] = (g.x >> 17) & 0x1FF;
    en_s[t] = g.y & 0x1FFFF;  q_s[t]  = (g.y >> 17) & 0x1FF;
  }
  __syncthreads();

  if (t < 256) {
    const int sedge = t >> 2, qq = t & 3;
    const float* hrow = node_emb + (size_t)hd_s[sedge] * 128;
    const float* erow = ent_table + (size_t)en_s[sedge] * 100;
#pragma unroll
    for (int j = 0; j < 4; ++j) {
      int c0 = j * 32 + qq * 8;
      float4 v0 = *(const float4*)(hrow + c0);
      float4 v1 = *(const float4*)(hrow + c0 + 4);
      bf16x8 pk;
      pk[0] = (short)f2bf(v0.x); pk[1] = (short)f2bf(v0.y);
      pk[2] = (short)f2bf(v0.z); pk[3] = (short)f2bf(v0.w);
      pk[4] = (short)f2bf(v1.x); pk[5] = (short)f2bf(v1.y);
      pk[6] = (short)f2bf(v1.z); pk[7] = (short)f2bf(v1.w);
      *(bf16x8*)&A0[sedge][c0] = pk;
    }
#pragma unroll
    for (int j = 0; j < 4; ++j) {
      int c0 = j * 32 + qq * 8;
      bf16x8 pk;
      if (c0 + 8 <= 100) {
        float4 v0 = *(const float4*)(erow + c0);
        float4 v1 = *(const float4*)(erow + c0 + 4);
        pk[0] = (short)f2bf(v0.x); pk[1] = (short)f2bf(v0.y);
        pk[2] = (short)f2bf(v0.z); pk[3] = (short)f2bf(v0.w);
        pk[4] = (short)f2bf(v1.x); pk[5] = (short)f2bf(v1.y);
        pk[6] = (short)f2bf(v1.z); pk[7] = (short)f2bf(v1.w);
      } else {
#pragma unroll
        for (int u = 0; u < 8; ++u) {
          float g = (c0 + u < 100) ? erow[c0 + u] : 0.f;
          pk[u] = (short)f2bf(g);
        }
      }
      *(bf16x8*)&A1[sedge][c0] = pk;
    }
  }
  __syncthreads();

  f32x4 acc[2][8];
  const f32x4 zz = {0.f, 0.f, 0.f, 0.f};
#pragma unroll
  for (int i = 0; i < 2; ++i)
#pragma unroll
    for (int j = 0; j < 8; ++j) acc[i][j] = zz;

  const unsigned short* wbase = Wcat + (size_t)c * 128 * 256;
  const int nkt = (c == 0) ? 4 : 8;
  for (int kt = 0; kt < nkt; ++kt) {
    bf16x8 bfr[8], afr[2];
#pragma unroll
    for (int ni = 0; ni < 8; ++ni)
      bfr[ni] = *(const bf16x8*)(wbase + (size_t)(ni * 16 + l15) * 256 + kt * 32 + l4 * 8);
    const int ci = (kt & 3) * 32 + l4 * 8;
    if (kt < 4) {
#pragma unroll
      for (int mi = 0; mi < 2; ++mi) afr[mi] = *(const bf16x8*)&A0[wm * 32 + mi * 16 + l15][ci];
    } else {
#pragma unroll
      for (int mi = 0; mi < 2; ++mi) afr[mi] = *(const bf16x8*)&A1[wm * 32 + mi * 16 + l15][ci];
    }
#pragma unroll
    for (int mi = 0; mi < 2; ++mi)
#pragma unroll
      for (int ni = 0; ni < 8; ++ni)
        acc[mi][ni] = __builtin_amdgcn_mfma_f32_16x16x32_bf16(afr[mi], bfr[ni], acc[mi][ni], 0, 0, 0);
  }
  __syncthreads();   // all A1 reads done before msg_s (alias) writes

  // ---- epilogue: per-wave on own acc ----
  if (c == 0) {
    float ba = b_a[0];
#pragma unroll
    for (int mi = 0; mi < 2; ++mi) {
      float p[4] = {0.f, 0.f, 0.f, 0.f};
#pragma unroll
      for (int r = 0; r < 4; ++r) {
        int el = wm * 32 + mi * 16 + l4 * 4 + r;
        const float* pr = P_r + (size_t)rl_s[el] * 128;
        const float* pq = P_qr + (size_t)q_s[el] * 128;
#pragma unroll
        for (int ni = 0; ni < 8; ++ni) {
          int h = ni * 16 + l15;
          float pre = acc[mi][ni][r] + pr[h] + pq[h];
          p[r] += Wa[h] * fmaxf(pre, 0.f);
        }
      }
#pragma unroll
      for (int off = 1; off < 16; off <<= 1) {
#pragma unroll
        for (int r = 0; r < 4; ++r) p[r] += __shfl_xor(p[r], off);
      }
      if (l15 == 0) {
#pragma unroll
        for (int r = 0; r < 4; ++r)
          ex_s[wm * 32 + mi * 16 + l4 * 4 + r] = expf(p[r] + ba);
      }
    }
  } else {
    // acc[mi][ni]: ni = gate*2 + hsel (gate r,z,xn,hn); h = s*32 + hsel*16 + l15
    const int s = c - 1;
    const int h0 = s * 32 + l15, h1 = h0 + 16;
    const float bh0 = b_hh[256 + h0], bh1 = b_hh[256 + h1];
#pragma unroll
    for (int mi = 0; mi < 2; ++mi) {
#pragma unroll
      for (int r = 0; r < 4; ++r) {
        int el = wm * 32 + mi * 16 + l4 * 4 + r;
        const float* Pb = P_ihr + (size_t)rl_s[el] * 384;
        float r0 = sigm(acc[mi][0][r] + Pb[h0]);
        float r1 = sigm(acc[mi][1][r] + Pb[h1]);
        float z0 = sigm(acc[mi][2][r] + Pb[128 + h0]);
        float z1 = sigm(acc[mi][3][r] + Pb[128 + h1]);
        float n0 = tanhf(acc[mi][4][r] + Pb[256 + h0] + r0 * (acc[mi][6][r] + bh0));
        float n1 = tanhf(acc[mi][5][r] + Pb[256 + h1] + r1 * (acc[mi][7][r] + bh1));
        float hs0 = bf2f(A0[el][h0]), hs1 = bf2f(A0[el][h1]);
        msg_s[el][h0] = f2bf((1.f - z0) * n0 + z0 * hs0);
        msg_s[el][h1] = f2bf((1.f - z1) * n1 + z1 * hs1);
      }
    }
  }
  __syncthreads();

  // ---- den leaders (t<64) + run-accumulated agg scatter (t 64..575) ----
  if (t < 64) {
    int tl = tl_s[t];
    bool lead = (tl >= 0) && (t == 0 || tl_s[t - 1] != tl);
    if (lead) {
      float ssum = 0.f;
      int i = t;
      while (i < 64 && tl_s[i] == tl) { ssum += ex_s[i]; ++i; }
      atomicAdd(&den[tl], ssum);
    }
  } else if (t < 576) {
    int ti = t - 64;
    int h = ti & 127, grp = ti >> 7;      // 4 groups x 16 edges
    float run = 0.f;
    int rt = -1;
    for (int k2 = 0; k2 < 16; ++k2) {
      int el = grp * 16 + k2;
      int tl = tl_s[el];
      if (tl >= 0) {
        float v = ex_s[el] * bf2f(msg_s[el][h]);
        if (tl != rt) {
          if (rt >= 0) atomicAdd(&agg[(size_t)rt * H_ + h], run);
          run = 0.f; rt = tl;
        }
        run += v;
      }
    }
    if (rt >= 0) atomicAdd(&agg[(size_t)rt * H_ + h], run);
  }
}

// ---- out = LayerNorm(relu((agg_raw/(den+eps)) @ Wh^T)), in place over d_out ----
__global__ __launch_bounds__(256) void k_out(
    const float* __restrict__ WhT, const float* __restrict__ ln_g, const float* __restrict__ ln_b,
    const float* __restrict__ den, float* __restrict__ out)
{
  __shared__ __align__(16) float a_s[16][H_];
  __shared__ float o_s[16][H_];
  __shared__ float mu_s[16], rs_s[16];
  const int tid = threadIdx.x;
  const size_t r0 = (size_t)blockIdx.x * 16;

  for (int idx = tid; idx < 16 * H_; idx += 256) {
    int r = idx >> 7, j = idx & (H_ - 1);
    float dv = den[r0 + r] + 1e-6f;
    a_s[r][j] = out[(r0 + r) * H_ + j] / dv;
  }
  __syncthreads();

  const int col = tid & 15, rr = tid >> 4;
  float acc[8] = {};
  for (int k4 = 0; k4 < H_ / 4; ++k4) {
    float4 a = ((const float4*)a_s[rr])[k4];
#pragma unroll
    for (int kk = 0; kk < 4; ++kk) {
      const float4* wrow = (const float4*)(WhT + (size_t)(k4 * 4 + kk) * H_);
      float av = ((const float*)&a)[kk];
      float4 w0 = wrow[col];
      float4 w1 = wrow[16 + col];
      acc[0] += av * w0.x; acc[1] += av * w0.y; acc[2] += av * w0.z; acc[3] += av * w0.w;
      acc[4] += av * w1.x; acc[5] += av * w1.y; acc[6] += av * w1.z; acc[7] += av * w1.w;
    }
  }
  float s = 0.f, sq = 0.f;
#pragma unroll
  for (int ci = 0; ci < 8; ++ci) {
    float v = fmaxf(acc[ci], 0.f);
    acc[ci] = v; s += v; sq += v * v;
  }
#pragma unroll
  for (int ci = 0; ci < 4; ++ci) {
    o_s[rr][col * 4 + ci]      = acc[ci];
    o_s[rr][64 + col * 4 + ci] = acc[4 + ci];
  }
#pragma unroll
  for (int off = 1; off < 16; off <<= 1) { s += __shfl_xor(s, off); sq += __shfl_xor(sq, off); }
  if (col == 0) {
    float mu = s * (1.f / H_);
    mu_s[rr] = mu;
    rs_s[rr] = rsqrtf(sq * (1.f / H_) - mu * mu + 1e-5f);
  }
  __syncthreads();
  for (int idx = tid; idx < 16 * H_; idx += 256) {
    int r = idx >> 7, j = idx & (H_ - 1);
    out[(r0 + r) * H_ + j] = ln_g[j] * (o_s[r][j] - mu_s[r]) * rs_s[r] + ln_b[j];
  }
}

extern "C" void kernel_launch(void* const* d_in, const int* in_sizes, int n_in,
                              void* d_out, int out_size, void* d_ws, size_t ws_size,
                              hipStream_t stream) {
  (void)in_sizes; (void)n_in; (void)ws_size;
  const int* head = (const int*)d_in[0];
  const int* rel  = (const int*)d_in[1];
  const int* ent  = (const int*)d_in[2];
  const int* tail = (const int*)d_in[3];
  const int* qidx = (const int*)d_in[4];
  const float* node_emb  = (const float*)d_in[5];
  const float* ent_table = (const float*)d_in[6];
  const float* rel_table = (const float*)d_in[7];
  const float* Ws   = (const float*)d_in[8];
  const float* Wr   = (const float*)d_in[9];
  const float* Wqr  = (const float*)d_in[10];
  const float* b_qr = (const float*)d_in[11];
  const float* Wa   = (const float*)d_in[12];
  const float* b_a  = (const float*)d_in[13];
  const float* W_ih = (const float*)d_in[14];
  const float* W_hh = (const float*)d_in[15];
  const float* b_ih = (const float*)d_in[16];
  const float* b_hh = (const float*)d_in[17];
  const float* Wh   = (const float*)d_in[18];
  const float* ln_g = (const float*)d_in[19];
  const float* ln_b = (const float*)d_in[20];
  float* out = (float*)d_out;

  // ws layout (bytes, all 16B-aligned):
  char* w = (char*)d_ws;
  float* den  = (float*)w;                         w += 400000;
  unsigned short* Wcat = (unsigned short*)w;       w += 640 * 256 * 2;
  float* WhT  = (float*)w;                         w += 65536;
  float* P_r  = (float*)w;                         w += 500 * 128 * 4;
  float* P_qr = (float*)w;                         w += 500 * 128 * 4;
  float* P_ihr= (float*)w;                         w += 500 * 384 * 4;
  int* cnt    = (int*)w;                           w += 400000;
  int* bsum   = (int*)w;                           w += 1024;
  int4* gs4   = (int4*)w;                          w += PERM2 * 16;

  hipMemsetAsync(den, 0, N_NEW_ * sizeof(float), stream);
  hipMemsetAsync(d_out, 0, (size_t)out_size * sizeof(float), stream);
  hipMemsetAsync(cnt, 0, N_NEW_ * sizeof(int), stream);
  hipMemsetAsync(gs4 + E_TOT, 0xFF, (PERM2 - E_TOT) * sizeof(int4), stream);  // pad tail=-1

  k_prep<<<(640 * 256 + 255) / 256, 256, 0, stream>>>(Ws, W_ih, W_hh, Wcat);
  k_transpose<<<(128 * 128 + 255) / 256, 256, 0, stream>>>(Wh, WhT, 128, 128);
  k_projrel<<<500, 256, 0, stream>>>(rel_table, Wr, Wqr, W_ih, b_qr, b_ih, b_hh,
                                     P_r, P_qr, P_ihr);

  // counting sort by tail -> packed sorted attributes
  k_hist<<<(E_TOT + 255) / 256, 256, 0, stream>>>(tail, cnt);
  k_scan1<<<(N_NEW_ + 511) / 512, 512, 0, stream>>>(cnt, bsum);
  k_scan2<<<1, 256, 0, stream>>>(bsum, (N_NEW_ + 511) / 512);
  k_scan3<<<(N_NEW_ + 255) / 256, 256, 0, stream>>>(cnt, bsum);
  k_scatterp<<<(E_TOT + 255) / 256, 256, 0, stream>>>(head, rel, ent, tail, qidx, cnt, gs4);

  k_edge<<<NBLK2, 640, 0, stream>>>(
      gs4, node_emb, ent_table, Wcat, P_r, P_qr, P_ihr, Wa, b_a, b_hh, den, out);

  k_out<<<N_NEW_ / 16, 256, 0, stream>>>(WhT, ln_g, ln_b, den, out);
}